// Round 1
// baseline (2334.514 us; speedup 1.0000x reference)
//
#include <hip/hip_runtime.h>

// GraphSAGE: 2x SAGEConv(mean) + ReLU, then linear out.
// N=40000 nodes, E=640000 edges, IN=H=128, OUT=64, fp32.

__global__ __launch_bounds__(256) void k_deg(const int* __restrict__ dst,
                                             float* __restrict__ deg, int E) {
  int e = blockIdx.x * 256 + threadIdx.x;
  if (e < E) atomicAdd(&deg[dst[e]], 1.0f);
}

__global__ __launch_bounds__(256) void k_inv(float* deg, int N) {
  int i = blockIdx.x * 256 + threadIdx.x;
  if (i < N) deg[i] = 1.0f / fmaxf(deg[i], 1.0f);
}

// Edge-parallel scatter-add: 32 threads per edge, float4 per thread (128 feats).
__global__ __launch_bounds__(256) void k_scatter(const float* __restrict__ feat,
                                                 const int* __restrict__ src,
                                                 const int* __restrict__ dst,
                                                 float* __restrict__ agg, int E) {
  int gid = blockIdx.x * 256 + threadIdx.x;
  int e = gid >> 5;
  if (e >= E) return;
  int c = (gid & 31) << 2;
  int s = src[e], d = dst[e];
  float4 v = *reinterpret_cast<const float4*>(feat + (size_t)s * 128 + c);
  float* p = agg + (size_t)d * 128 + c;
  atomicAdd(p + 0, v.x);
  atomicAdd(p + 1, v.y);
  atomicAdd(p + 2, v.z);
  atomicAdd(p + 3, v.w);
}

// Fused SAGE layer: out = relu([agg*invdeg | root] @ [Wl; Wr] + b)
// Tile: 64 nodes x 128 cols per block, 256 threads, each 8 nodes x 4 cols.
template <bool RELU>
__global__ __launch_bounds__(256) void k_sage_gemm(
    const float* __restrict__ agg, const float* __restrict__ invdeg,
    const float* __restrict__ root, const float* __restrict__ Wl,
    const float* __restrict__ Wr, const float* __restrict__ bias,
    float* __restrict__ out, int M) {
  __shared__ float A[32][68];   // [kk][node], padded
  __shared__ float B[32][132];  // [kk][col], padded
  const int tid = threadIdx.x;
  const int tx = tid & 31;   // col group: cols tx*4 .. +3
  const int ty = tid >> 5;   // node group: nodes ty*8 .. +7
  const int m0 = blockIdx.x * 64;
  float acc[8][4] = {};

  for (int k0 = 0; k0 < 256; k0 += 32) {
    __syncthreads();
    const bool isAgg = (k0 < 128);
    // A tile: 64 rows x 32 k, store transposed
#pragma unroll
    for (int j = 0; j < 2; ++j) {
      int idx = tid + j * 256;       // 0..511 float4s
      int r = idx >> 3;              // row 0..63
      int c = (idx & 7) << 2;        // k offset 0,4,..,28
      int node = m0 + r;
      if (node >= M) node = M - 1;   // clamp (M divisible by 64 here anyway)
      float4 v;
      if (isAgg) {
        v = *reinterpret_cast<const float4*>(agg + (size_t)node * 128 + k0 + c);
        float s = invdeg[node];
        v.x *= s; v.y *= s; v.z *= s; v.w *= s;
      } else {
        v = *reinterpret_cast<const float4*>(root + (size_t)node * 128 + (k0 - 128) + c);
      }
      A[c + 0][r] = v.x; A[c + 1][r] = v.y; A[c + 2][r] = v.z; A[c + 3][r] = v.w;
    }
    // B tile: 32 k x 128 cols
    const float* W = isAgg ? (Wl + (size_t)k0 * 128) : (Wr + (size_t)(k0 - 128) * 128);
#pragma unroll
    for (int j = 0; j < 4; ++j) {
      int idx = tid + j * 256;       // 0..1023 float4s
      int kk = idx >> 5;
      int c = (idx & 31) << 2;
      float4 v = *reinterpret_cast<const float4*>(W + kk * 128 + c);
      *reinterpret_cast<float4*>(&B[kk][c]) = v;
    }
    __syncthreads();
#pragma unroll 8
    for (int kk = 0; kk < 32; ++kk) {
      float4 b4 = *reinterpret_cast<float4*>(&B[kk][tx * 4]);
      float4 a0 = *reinterpret_cast<float4*>(&A[kk][ty * 8]);
      float4 a1 = *reinterpret_cast<float4*>(&A[kk][ty * 8 + 4]);
      float a[8] = {a0.x, a0.y, a0.z, a0.w, a1.x, a1.y, a1.z, a1.w};
#pragma unroll
      for (int i = 0; i < 8; ++i) {
        acc[i][0] = fmaf(a[i], b4.x, acc[i][0]);
        acc[i][1] = fmaf(a[i], b4.y, acc[i][1]);
        acc[i][2] = fmaf(a[i], b4.z, acc[i][2]);
        acc[i][3] = fmaf(a[i], b4.w, acc[i][3]);
      }
    }
  }
  float4 bv = *reinterpret_cast<const float4*>(bias + tx * 4);
#pragma unroll
  for (int i = 0; i < 8; ++i) {
    int node = m0 + ty * 8 + i;
    if (node >= M) continue;
    float4 r;
    r.x = acc[i][0] + bv.x;
    r.y = acc[i][1] + bv.y;
    r.z = acc[i][2] + bv.z;
    r.w = acc[i][3] + bv.w;
    if (RELU) {
      r.x = fmaxf(r.x, 0.f); r.y = fmaxf(r.y, 0.f);
      r.z = fmaxf(r.z, 0.f); r.w = fmaxf(r.w, 0.f);
    }
    *reinterpret_cast<float4*>(out + (size_t)node * 128 + tx * 4) = r;
  }
}

// out = h @ Wout + bout ; tile 64 nodes x 64 cols, each thread 4x4.
__global__ __launch_bounds__(256) void k_out_gemm(
    const float* __restrict__ h, const float* __restrict__ Wout,
    const float* __restrict__ bias, float* __restrict__ out, int M) {
  __shared__ float A[32][68];
  __shared__ float B[32][68];
  const int tid = threadIdx.x;
  const int tx = tid & 15;   // col group *4
  const int ty = tid >> 4;   // node group *4
  const int m0 = blockIdx.x * 64;
  float acc[4][4] = {};
  for (int k0 = 0; k0 < 128; k0 += 32) {
    __syncthreads();
#pragma unroll
    for (int j = 0; j < 2; ++j) {
      int idx = tid + j * 256;
      int r = idx >> 3;
      int c = (idx & 7) << 2;
      int node = m0 + r;
      if (node >= M) node = M - 1;
      float4 v = *reinterpret_cast<const float4*>(h + (size_t)node * 128 + k0 + c);
      A[c + 0][r] = v.x; A[c + 1][r] = v.y; A[c + 2][r] = v.z; A[c + 3][r] = v.w;
    }
#pragma unroll
    for (int j = 0; j < 2; ++j) {
      int idx = tid + j * 256;       // 0..511 float4s = 32x64 floats
      int kk = idx >> 4;
      int c = (idx & 15) << 2;
      float4 v = *reinterpret_cast<const float4*>(Wout + (size_t)(k0 + kk) * 64 + c);
      *reinterpret_cast<float4*>(&B[kk][c]) = v;
    }
    __syncthreads();
#pragma unroll 8
    for (int kk = 0; kk < 32; ++kk) {
      float4 b4 = *reinterpret_cast<float4*>(&B[kk][tx * 4]);
      float4 a4 = *reinterpret_cast<float4*>(&A[kk][ty * 4]);
      float a[4] = {a4.x, a4.y, a4.z, a4.w};
#pragma unroll
      for (int i = 0; i < 4; ++i) {
        acc[i][0] = fmaf(a[i], b4.x, acc[i][0]);
        acc[i][1] = fmaf(a[i], b4.y, acc[i][1]);
        acc[i][2] = fmaf(a[i], b4.z, acc[i][2]);
        acc[i][3] = fmaf(a[i], b4.w, acc[i][3]);
      }
    }
  }
  float4 bv = *reinterpret_cast<const float4*>(bias + tx * 4);
#pragma unroll
  for (int i = 0; i < 4; ++i) {
    int node = m0 + ty * 4 + i;
    if (node >= M) continue;
    float4 r;
    r.x = acc[i][0] + bv.x;
    r.y = acc[i][1] + bv.y;
    r.z = acc[i][2] + bv.z;
    r.w = acc[i][3] + bv.w;
    *reinterpret_cast<float4*>(out + (size_t)node * 64 + tx * 4) = r;
  }
}

extern "C" void kernel_launch(void* const* d_in, const int* in_sizes, int n_in,
                              void* d_out, int out_size, void* d_ws, size_t ws_size,
                              hipStream_t stream) {
  const float* x    = (const float*)d_in[0];
  const int*   ei   = (const int*)d_in[1];
  const float* W1l  = (const float*)d_in[2];
  const float* W1r  = (const float*)d_in[3];
  const float* b1   = (const float*)d_in[4];
  const float* W2l  = (const float*)d_in[5];
  const float* W2r  = (const float*)d_in[6];
  const float* b2   = (const float*)d_in[7];
  const float* Wout = (const float*)d_in[8];
  const float* bout = (const float*)d_in[9];
  float* out = (float*)d_out;

  const int N = in_sizes[0] / 128;
  const int E = in_sizes[1] / 2;
  const int* src = ei;
  const int* dst = ei + E;

  char* ws = (char*)d_ws;
  float* deg  = (float*)ws;  // N floats
  size_t degBytes = ((size_t)N * 4 + 255) & ~(size_t)255;
  float* bufA = (float*)(ws + degBytes);        // N*128 (agg)
  float* bufB = bufA + (size_t)N * 128;         // N*128 (h)
  size_t featBytes = (size_t)N * 128 * 4;

  hipMemsetAsync(deg, 0, (size_t)N * 4, stream);
  hipMemsetAsync(bufA, 0, featBytes, stream);

  int scatterBlocks = (int)(((size_t)E * 32 + 255) / 256);
  int gemmBlocks = (N + 63) / 64;

  k_deg<<<(E + 255) / 256, 256, 0, stream>>>(dst, deg, E);
  k_inv<<<(N + 255) / 256, 256, 0, stream>>>(deg, N);

  // Layer 1
  k_scatter<<<scatterBlocks, 256, 0, stream>>>(x, src, dst, bufA, E);
  k_sage_gemm<true><<<gemmBlocks, 256, 0, stream>>>(bufA, deg, x, W1l, W1r, b1, bufB, N);

  // Layer 2
  hipMemsetAsync(bufA, 0, featBytes, stream);
  k_scatter<<<scatterBlocks, 256, 0, stream>>>(bufB, src, dst, bufA, E);
  k_sage_gemm<true><<<gemmBlocks, 256, 0, stream>>>(bufA, deg, bufB, W2l, W2r, b2, bufB, N);

  // Output projection
  k_out_gemm<<<gemmBlocks, 256, 0, stream>>>(bufB, Wout, bout, out, N);
}

// Round 2
// 347.830 us; speedup vs baseline: 6.7117x; 6.7117x over previous
//
#include <hip/hip_runtime.h>

// GraphSAGE: 2x SAGEConv(mean) + ReLU, then linear out.
// N=40000 nodes, E=640000 edges, IN=H=128, OUT=64, fp32.
// Round 2: CSR gather aggregation replaces atomic scatter.

__global__ __launch_bounds__(256) void k_hist(const int* __restrict__ dst,
                                              int* __restrict__ cnt, int E) {
  int e = blockIdx.x * 256 + threadIdx.x;
  if (e < E) atomicAdd(&cnt[dst[e]], 1);
}

// Single-workgroup exclusive scan over N counts -> rowptr (and cursor copy).
__global__ __launch_bounds__(1024) void k_scan(const int* __restrict__ cnt,
                                               int* __restrict__ rowptr,
                                               int* __restrict__ cursor, int N) {
  __shared__ int warpSums[16];
  __shared__ int running;
  const int tid = threadIdx.x;
  const int lane = tid & 63, wid = tid >> 6;
  if (tid == 0) running = 0;
  __syncthreads();
  for (int i0 = 0; i0 < N; i0 += 1024) {
    int i = i0 + tid;
    int v = (i < N) ? cnt[i] : 0;
    int s = v;
#pragma unroll
    for (int d = 1; d < 64; d <<= 1) {
      int t = __shfl_up(s, d, 64);
      if (lane >= d) s += t;
    }
    if (lane == 63) warpSums[wid] = s;
    __syncthreads();
    if (tid < 16) {
      int w = warpSums[tid];
#pragma unroll
      for (int d = 1; d < 16; d <<= 1) {
        int t = __shfl_up(w, d, 16);
        if (tid >= d) w += t;
      }
      warpSums[tid] = w;
    }
    __syncthreads();
    int base = running + (wid ? warpSums[wid - 1] : 0);
    if (i < N) {
      int ex = base + s - v;
      rowptr[i] = ex;
      cursor[i] = ex;
    }
    __syncthreads();
    if (tid == 0) running += warpSums[15];
    __syncthreads();
  }
  if (tid == 0) rowptr[N] = running;
}

__global__ __launch_bounds__(256) void k_fill(const int* __restrict__ src,
                                              const int* __restrict__ dst,
                                              int* __restrict__ cursor,
                                              int* __restrict__ csr_src, int E) {
  int e = blockIdx.x * 256 + threadIdx.x;
  if (e < E) {
    int pos = atomicAdd(&cursor[dst[e]], 1);
    csr_src[pos] = src[e];
  }
}

// One wave per node: mean of neighbor feature rows (128 f32, float2/lane).
__global__ __launch_bounds__(256) void k_agg(const float* __restrict__ feat,
                                             const int* __restrict__ rowptr,
                                             const int* __restrict__ csr_src,
                                             float* __restrict__ agg, int N) {
  int node = (blockIdx.x * 256 + threadIdx.x) >> 6;
  if (node >= N) return;
  int lane = threadIdx.x & 63;
  int beg = rowptr[node], end = rowptr[node + 1];
  const int c = lane * 2;
  float2 s = {0.f, 0.f};
  for (int j = beg; j < end; ++j) {
    int sn = csr_src[j];
    float2 v = *reinterpret_cast<const float2*>(feat + (size_t)sn * 128 + c);
    s.x += v.x;
    s.y += v.y;
  }
  float invd = 1.0f / fmaxf((float)(end - beg), 1.0f);
  s.x *= invd;
  s.y *= invd;
  *reinterpret_cast<float2*>(agg + (size_t)node * 128 + c) = s;
}

// Fused SAGE layer: out = relu([agg | root] @ [Wl; Wr] + b)   (agg pre-mean'd)
// Tile: 64 nodes x 128 cols per block, 256 threads, each 8 nodes x 4 cols.
template <bool RELU>
__global__ __launch_bounds__(256) void k_sage_gemm(
    const float* __restrict__ agg, const float* __restrict__ root,
    const float* __restrict__ Wl, const float* __restrict__ Wr,
    const float* __restrict__ bias, float* __restrict__ out, int M) {
  __shared__ float A[32][68];   // [kk][node], padded
  __shared__ float B[32][132];  // [kk][col], padded
  const int tid = threadIdx.x;
  const int tx = tid & 31;   // col group: cols tx*4 .. +3
  const int ty = tid >> 5;   // node group: nodes ty*8 .. +7
  const int m0 = blockIdx.x * 64;
  float acc[8][4] = {};

  for (int k0 = 0; k0 < 256; k0 += 32) {
    __syncthreads();
    const bool isAgg = (k0 < 128);
    const float* Asrc = isAgg ? agg : root;
    const int kbase = isAgg ? k0 : (k0 - 128);
#pragma unroll
    for (int j = 0; j < 2; ++j) {
      int idx = tid + j * 256;       // 0..511 float4s
      int r = idx >> 3;              // row 0..63
      int c = (idx & 7) << 2;        // k offset
      int node = m0 + r;
      if (node >= M) node = M - 1;
      float4 v = *reinterpret_cast<const float4*>(Asrc + (size_t)node * 128 + kbase + c);
      A[c + 0][r] = v.x; A[c + 1][r] = v.y; A[c + 2][r] = v.z; A[c + 3][r] = v.w;
    }
    const float* W = isAgg ? (Wl + (size_t)k0 * 128) : (Wr + (size_t)(k0 - 128) * 128);
#pragma unroll
    for (int j = 0; j < 4; ++j) {
      int idx = tid + j * 256;       // 0..1023 float4s
      int kk = idx >> 5;
      int c = (idx & 31) << 2;
      float4 v = *reinterpret_cast<const float4*>(W + kk * 128 + c);
      *reinterpret_cast<float4*>(&B[kk][c]) = v;
    }
    __syncthreads();
#pragma unroll 8
    for (int kk = 0; kk < 32; ++kk) {
      float4 b4 = *reinterpret_cast<float4*>(&B[kk][tx * 4]);
      float4 a0 = *reinterpret_cast<float4*>(&A[kk][ty * 8]);
      float4 a1 = *reinterpret_cast<float4*>(&A[kk][ty * 8 + 4]);
      float a[8] = {a0.x, a0.y, a0.z, a0.w, a1.x, a1.y, a1.z, a1.w};
#pragma unroll
      for (int i = 0; i < 8; ++i) {
        acc[i][0] = fmaf(a[i], b4.x, acc[i][0]);
        acc[i][1] = fmaf(a[i], b4.y, acc[i][1]);
        acc[i][2] = fmaf(a[i], b4.z, acc[i][2]);
        acc[i][3] = fmaf(a[i], b4.w, acc[i][3]);
      }
    }
  }
  float4 bv = *reinterpret_cast<const float4*>(bias + tx * 4);
#pragma unroll
  for (int i = 0; i < 8; ++i) {
    int node = m0 + ty * 8 + i;
    if (node >= M) continue;
    float4 r;
    r.x = acc[i][0] + bv.x;
    r.y = acc[i][1] + bv.y;
    r.z = acc[i][2] + bv.z;
    r.w = acc[i][3] + bv.w;
    if (RELU) {
      r.x = fmaxf(r.x, 0.f); r.y = fmaxf(r.y, 0.f);
      r.z = fmaxf(r.z, 0.f); r.w = fmaxf(r.w, 0.f);
    }
    *reinterpret_cast<float4*>(out + (size_t)node * 128 + tx * 4) = r;
  }
}

// out = h @ Wout + bout ; tile 64 nodes x 64 cols, each thread 4x4.
__global__ __launch_bounds__(256) void k_out_gemm(
    const float* __restrict__ h, const float* __restrict__ Wout,
    const float* __restrict__ bias, float* __restrict__ out, int M) {
  __shared__ float A[32][68];
  __shared__ float B[32][68];
  const int tid = threadIdx.x;
  const int tx = tid & 15;
  const int ty = tid >> 4;
  const int m0 = blockIdx.x * 64;
  float acc[4][4] = {};
  for (int k0 = 0; k0 < 128; k0 += 32) {
    __syncthreads();
#pragma unroll
    for (int j = 0; j < 2; ++j) {
      int idx = tid + j * 256;
      int r = idx >> 3;
      int c = (idx & 7) << 2;
      int node = m0 + r;
      if (node >= M) node = M - 1;
      float4 v = *reinterpret_cast<const float4*>(h + (size_t)node * 128 + k0 + c);
      A[c + 0][r] = v.x; A[c + 1][r] = v.y; A[c + 2][r] = v.z; A[c + 3][r] = v.w;
    }
#pragma unroll
    for (int j = 0; j < 2; ++j) {
      int idx = tid + j * 256;       // 32x64 floats
      int kk = idx >> 4;
      int c = (idx & 15) << 2;
      float4 v = *reinterpret_cast<const float4*>(Wout + (size_t)(k0 + kk) * 64 + c);
      *reinterpret_cast<float4*>(&B[kk][c]) = v;
    }
    __syncthreads();
#pragma unroll 8
    for (int kk = 0; kk < 32; ++kk) {
      float4 b4 = *reinterpret_cast<float4*>(&B[kk][tx * 4]);
      float4 a4 = *reinterpret_cast<float4*>(&A[kk][ty * 4]);
      float a[4] = {a4.x, a4.y, a4.z, a4.w};
#pragma unroll
      for (int i = 0; i < 4; ++i) {
        acc[i][0] = fmaf(a[i], b4.x, acc[i][0]);
        acc[i][1] = fmaf(a[i], b4.y, acc[i][1]);
        acc[i][2] = fmaf(a[i], b4.z, acc[i][2]);
        acc[i][3] = fmaf(a[i], b4.w, acc[i][3]);
      }
    }
  }
  float4 bv = *reinterpret_cast<const float4*>(bias + tx * 4);
#pragma unroll
  for (int i = 0; i < 4; ++i) {
    int node = m0 + ty * 4 + i;
    if (node >= M) continue;
    float4 r;
    r.x = acc[i][0] + bv.x;
    r.y = acc[i][1] + bv.y;
    r.z = acc[i][2] + bv.z;
    r.w = acc[i][3] + bv.w;
    *reinterpret_cast<float4*>(out + (size_t)node * 64 + tx * 4) = r;
  }
}

extern "C" void kernel_launch(void* const* d_in, const int* in_sizes, int n_in,
                              void* d_out, int out_size, void* d_ws, size_t ws_size,
                              hipStream_t stream) {
  const float* x    = (const float*)d_in[0];
  const int*   ei   = (const int*)d_in[1];
  const float* W1l  = (const float*)d_in[2];
  const float* W1r  = (const float*)d_in[3];
  const float* b1   = (const float*)d_in[4];
  const float* W2l  = (const float*)d_in[5];
  const float* W2r  = (const float*)d_in[6];
  const float* b2   = (const float*)d_in[7];
  const float* Wout = (const float*)d_in[8];
  const float* bout = (const float*)d_in[9];
  float* out = (float*)d_out;

  const int N = in_sizes[0] / 128;
  const int E = in_sizes[1] / 2;
  const int* src = ei;
  const int* dst = ei + E;

  auto align = [](size_t b) { return (b + 255) & ~(size_t)255; };
  char* ws = (char*)d_ws;
  int* cnt     = (int*)ws;                    ws += align((size_t)N * 4);
  int* rowptr  = (int*)ws;                    ws += align((size_t)(N + 1) * 4);
  int* cursor  = (int*)ws;                    ws += align((size_t)N * 4);
  int* csr_src = (int*)ws;                    ws += align((size_t)E * 4);
  float* bufA  = (float*)ws;                  ws += (size_t)N * 128 * 4;
  float* bufB  = (float*)ws;

  hipMemsetAsync(cnt, 0, (size_t)N * 4, stream);

  const int gemmBlocks = (N + 63) / 64;
  const int aggBlocks = (N + 3) / 4;  // 4 waves/block, 1 node/wave

  // CSR build (per launch; edge_index is constant but no caching allowed)
  k_hist<<<(E + 255) / 256, 256, 0, stream>>>(dst, cnt, E);
  k_scan<<<1, 1024, 0, stream>>>(cnt, rowptr, cursor, N);
  k_fill<<<(E + 255) / 256, 256, 0, stream>>>(src, dst, cursor, csr_src, E);

  // Layer 1
  k_agg<<<aggBlocks, 256, 0, stream>>>(x, rowptr, csr_src, bufA, N);
  k_sage_gemm<true><<<gemmBlocks, 256, 0, stream>>>(bufA, x, W1l, W1r, b1, bufB, N);

  // Layer 2
  k_agg<<<aggBlocks, 256, 0, stream>>>(bufB, rowptr, csr_src, bufA, N);
  k_sage_gemm<true><<<gemmBlocks, 256, 0, stream>>>(bufA, bufB, W2l, W2r, b2, bufB, N);

  // Output projection
  k_out_gemm<<<gemmBlocks, 256, 0, stream>>>(bufB, Wout, bout, out, N);
}

// Round 5
// 271.507 us; speedup vs baseline: 8.5984x; 1.2811x over previous
//
#include <hip/hip_runtime.h>

// GraphSAGE: 2x SAGEConv(mean) + ReLU, then linear out.
// N=40000, E=640000, IN=H=128, OUT=64. ALL-f32 (round-2 numerics, proven).
// Round 5: 4-row-in-flight f32 agg + parallel CSR scan. Workspace layout
// byte-identical to round 2 (proven fit).

__global__ __launch_bounds__(256) void k_hist(const int* __restrict__ dst,
                                              int* __restrict__ cnt, int E) {
  int e = blockIdx.x * 256 + threadIdx.x;
  if (e < E) atomicAdd(&cnt[dst[e]], 1);
}

// Per-1024-block sums of cnt -> blockSums[b]
__global__ __launch_bounds__(1024) void k_bsum(const int* __restrict__ cnt,
                                               int* __restrict__ blockSums, int N) {
  __shared__ int ws[16];
  int i = blockIdx.x * 1024 + threadIdx.x;
  int v = (i < N) ? cnt[i] : 0;
#pragma unroll
  for (int d = 32; d > 0; d >>= 1) v += __shfl_xor(v, d, 64);
  if ((threadIdx.x & 63) == 0) ws[threadIdx.x >> 6] = v;
  __syncthreads();
  if (threadIdx.x == 0) {
    int s = 0;
#pragma unroll
    for (int w = 0; w < 16; ++w) s += ws[w];
    blockSums[blockIdx.x] = s;
  }
}

// Tiny serial scan of nb block sums (nb=40) -> blockOff; rowptr[N]=total.
__global__ __launch_bounds__(64) void k_bscan(const int* __restrict__ blockSums,
                                              int* __restrict__ blockOff,
                                              int* __restrict__ rowptr, int nb, int N) {
  if (threadIdx.x == 0) {
    int run = 0;
    for (int i = 0; i < nb; ++i) {
      blockOff[i] = run;
      run += blockSums[i];
    }
    rowptr[N] = run;
  }
}

// Per-block exclusive scan of cnt + blockOff -> rowptr, cursor.
__global__ __launch_bounds__(1024) void k_escan(const int* __restrict__ cnt,
                                                const int* __restrict__ blockOff,
                                                int* __restrict__ rowptr,
                                                int* __restrict__ cursor, int N) {
  __shared__ int warpSums[16];
  const int tid = threadIdx.x;
  const int lane = tid & 63, wid = tid >> 6;
  int i = blockIdx.x * 1024 + tid;
  int v = (i < N) ? cnt[i] : 0;
  int s = v;
#pragma unroll
  for (int d = 1; d < 64; d <<= 1) {
    int t = __shfl_up(s, d, 64);
    if (lane >= d) s += t;
  }
  if (lane == 63) warpSums[wid] = s;
  __syncthreads();
  if (tid < 16) {
    int w = warpSums[tid];
#pragma unroll
    for (int d = 1; d < 16; d <<= 1) {
      int t = __shfl_up(w, d, 16);
      if (tid >= d) w += t;
    }
    warpSums[tid] = w;
  }
  __syncthreads();
  int ex = blockOff[blockIdx.x] + (wid ? warpSums[wid - 1] : 0) + s - v;
  if (i < N) {
    rowptr[i] = ex;
    cursor[i] = ex;
  }
}

__global__ __launch_bounds__(256) void k_fill(const int* __restrict__ src,
                                              const int* __restrict__ dst,
                                              int* __restrict__ cursor,
                                              int* __restrict__ csr_src, int E) {
  int e = blockIdx.x * 256 + threadIdx.x;
  if (e < E) {
    int pos = atomicAdd(&cursor[dst[e]], 1);
    csr_src[pos] = src[e];
  }
}

// One wave per node: mean of f32 neighbor rows (128 feats).
// 64 lanes x float2 per row; 4 rows in flight per iteration.
__global__ __launch_bounds__(256) void k_agg(const float* __restrict__ feat,
                                             const int* __restrict__ rowptr,
                                             const int* __restrict__ csr_src,
                                             float* __restrict__ agg, int N) {
  int node = (blockIdx.x * 256 + threadIdx.x) >> 6;
  if (node >= N) return;
  const int lane = threadIdx.x & 63;
  const int beg = rowptr[node];
  const int deg = rowptr[node + 1] - beg;
  const int c = lane * 2;
  float2 a0 = {0.f, 0.f}, a1 = {0.f, 0.f}, a2 = {0.f, 0.f}, a3 = {0.f, 0.f};
  int j = 0;
  for (; j + 3 < deg; j += 4) {
    int s0 = csr_src[beg + j + 0];
    int s1 = csr_src[beg + j + 1];
    int s2 = csr_src[beg + j + 2];
    int s3 = csr_src[beg + j + 3];
    float2 v0 = *reinterpret_cast<const float2*>(feat + (size_t)s0 * 128 + c);
    float2 v1 = *reinterpret_cast<const float2*>(feat + (size_t)s1 * 128 + c);
    float2 v2 = *reinterpret_cast<const float2*>(feat + (size_t)s2 * 128 + c);
    float2 v3 = *reinterpret_cast<const float2*>(feat + (size_t)s3 * 128 + c);
    a0.x += v0.x; a0.y += v0.y;
    a1.x += v1.x; a1.y += v1.y;
    a2.x += v2.x; a2.y += v2.y;
    a3.x += v3.x; a3.y += v3.y;
  }
  for (; j < deg; ++j) {
    int s0 = csr_src[beg + j];
    float2 v0 = *reinterpret_cast<const float2*>(feat + (size_t)s0 * 128 + c);
    a0.x += v0.x; a0.y += v0.y;
  }
  float invd = 1.0f / fmaxf((float)deg, 1.0f);
  float2 o;
  o.x = (a0.x + a1.x + a2.x + a3.x) * invd;
  o.y = (a0.y + a1.y + a2.y + a3.y) * invd;
  *reinterpret_cast<float2*>(agg + (size_t)node * 128 + c) = o;
}

// Fused SAGE layer: out = relu([agg | root] @ [Wl; Wr] + b)   (round-2 proven)
// Tile: 64 nodes x 128 cols per block, 256 threads, each 8 nodes x 4 cols.
template <bool RELU>
__global__ __launch_bounds__(256) void k_sage_gemm(
    const float* __restrict__ agg, const float* __restrict__ root,
    const float* __restrict__ Wl, const float* __restrict__ Wr,
    const float* __restrict__ bias, float* __restrict__ out, int M) {
  __shared__ float A[32][68];   // [kk][node], padded
  __shared__ float B[32][132];  // [kk][col], padded
  const int tid = threadIdx.x;
  const int tx = tid & 31;
  const int ty = tid >> 5;
  const int m0 = blockIdx.x * 64;
  float acc[8][4] = {};

  for (int k0 = 0; k0 < 256; k0 += 32) {
    __syncthreads();
    const bool isAgg = (k0 < 128);
    const float* Asrc = isAgg ? agg : root;
    const int kbase = isAgg ? k0 : (k0 - 128);
#pragma unroll
    for (int j = 0; j < 2; ++j) {
      int idx = tid + j * 256;
      int r = idx >> 3;
      int c = (idx & 7) << 2;
      int node = m0 + r;
      if (node >= M) node = M - 1;
      float4 v = *reinterpret_cast<const float4*>(Asrc + (size_t)node * 128 + kbase + c);
      A[c + 0][r] = v.x; A[c + 1][r] = v.y; A[c + 2][r] = v.z; A[c + 3][r] = v.w;
    }
    const float* W = isAgg ? (Wl + (size_t)k0 * 128) : (Wr + (size_t)(k0 - 128) * 128);
#pragma unroll
    for (int j = 0; j < 4; ++j) {
      int idx = tid + j * 256;
      int kk = idx >> 5;
      int c = (idx & 31) << 2;
      float4 v = *reinterpret_cast<const float4*>(W + kk * 128 + c);
      *reinterpret_cast<float4*>(&B[kk][c]) = v;
    }
    __syncthreads();
#pragma unroll 8
    for (int kk = 0; kk < 32; ++kk) {
      float4 b4 = *reinterpret_cast<float4*>(&B[kk][tx * 4]);
      float4 a0 = *reinterpret_cast<float4*>(&A[kk][ty * 8]);
      float4 a1 = *reinterpret_cast<float4*>(&A[kk][ty * 8 + 4]);
      float a[8] = {a0.x, a0.y, a0.z, a0.w, a1.x, a1.y, a1.z, a1.w};
#pragma unroll
      for (int i = 0; i < 8; ++i) {
        acc[i][0] = fmaf(a[i], b4.x, acc[i][0]);
        acc[i][1] = fmaf(a[i], b4.y, acc[i][1]);
        acc[i][2] = fmaf(a[i], b4.z, acc[i][2]);
        acc[i][3] = fmaf(a[i], b4.w, acc[i][3]);
      }
    }
  }
  float4 bv = *reinterpret_cast<const float4*>(bias + tx * 4);
#pragma unroll
  for (int i = 0; i < 8; ++i) {
    int node = m0 + ty * 8 + i;
    if (node >= M) continue;
    float4 r;
    r.x = acc[i][0] + bv.x;
    r.y = acc[i][1] + bv.y;
    r.z = acc[i][2] + bv.z;
    r.w = acc[i][3] + bv.w;
    if (RELU) {
      r.x = fmaxf(r.x, 0.f); r.y = fmaxf(r.y, 0.f);
      r.z = fmaxf(r.z, 0.f); r.w = fmaxf(r.w, 0.f);
    }
    *reinterpret_cast<float4*>(out + (size_t)node * 128 + tx * 4) = r;
  }
}

// out = h @ Wout + bout ; tile 64 nodes x 64 cols, each thread 4x4. (proven)
__global__ __launch_bounds__(256) void k_out_gemm(
    const float* __restrict__ h, const float* __restrict__ Wout,
    const float* __restrict__ bias, float* __restrict__ out, int M) {
  __shared__ float A[32][68];
  __shared__ float B[32][68];
  const int tid = threadIdx.x;
  const int tx = tid & 15;
  const int ty = tid >> 4;
  const int m0 = blockIdx.x * 64;
  float acc[4][4] = {};
  for (int k0 = 0; k0 < 128; k0 += 32) {
    __syncthreads();
#pragma unroll
    for (int j = 0; j < 2; ++j) {
      int idx = tid + j * 256;
      int r = idx >> 3;
      int c = (idx & 7) << 2;
      int node = m0 + r;
      if (node >= M) node = M - 1;
      float4 v = *reinterpret_cast<const float4*>(h + (size_t)node * 128 + k0 + c);
      A[c + 0][r] = v.x; A[c + 1][r] = v.y; A[c + 2][r] = v.z; A[c + 3][r] = v.w;
    }
#pragma unroll
    for (int j = 0; j < 2; ++j) {
      int idx = tid + j * 256;
      int kk = idx >> 4;
      int c = (idx & 15) << 2;
      float4 v = *reinterpret_cast<const float4*>(Wout + (size_t)(k0 + kk) * 64 + c);
      *reinterpret_cast<float4*>(&B[kk][c]) = v;
    }
    __syncthreads();
#pragma unroll 8
    for (int kk = 0; kk < 32; ++kk) {
      float4 b4 = *reinterpret_cast<float4*>(&B[kk][tx * 4]);
      float4 a4 = *reinterpret_cast<float4*>(&A[kk][ty * 4]);
      float a[4] = {a4.x, a4.y, a4.z, a4.w};
#pragma unroll
      for (int i = 0; i < 4; ++i) {
        acc[i][0] = fmaf(a[i], b4.x, acc[i][0]);
        acc[i][1] = fmaf(a[i], b4.y, acc[i][1]);
        acc[i][2] = fmaf(a[i], b4.z, acc[i][2]);
        acc[i][3] = fmaf(a[i], b4.w, acc[i][3]);
      }
    }
  }
  float4 bv = *reinterpret_cast<const float4*>(bias + tx * 4);
#pragma unroll
  for (int i = 0; i < 4; ++i) {
    int node = m0 + ty * 4 + i;
    if (node >= M) continue;
    float4 r;
    r.x = acc[i][0] + bv.x;
    r.y = acc[i][1] + bv.y;
    r.z = acc[i][2] + bv.z;
    r.w = acc[i][3] + bv.w;
    *reinterpret_cast<float4*>(out + (size_t)node * 64 + tx * 4) = r;
  }
}

extern "C" void kernel_launch(void* const* d_in, const int* in_sizes, int n_in,
                              void* d_out, int out_size, void* d_ws, size_t ws_size,
                              hipStream_t stream) {
  const float* x    = (const float*)d_in[0];
  const int*   ei   = (const int*)d_in[1];
  const float* W1l  = (const float*)d_in[2];
  const float* W1r  = (const float*)d_in[3];
  const float* b1   = (const float*)d_in[4];
  const float* W2l  = (const float*)d_in[5];
  const float* W2r  = (const float*)d_in[6];
  const float* b2   = (const float*)d_in[7];
  const float* Wout = (const float*)d_in[8];
  const float* bout = (const float*)d_in[9];
  float* out = (float*)d_out;

  const int N = in_sizes[0] / 128;
  const int E = in_sizes[1] / 2;
  const int* src = ei;
  const int* dst = ei + E;

  // Workspace layout byte-identical to round 2 (proven fit).
  auto align = [](size_t b) { return (b + 255) & ~(size_t)255; };
  char* p = (char*)d_ws;
  int* cnt     = (int*)p;   p += align((size_t)N * 4);
  int* rowptr  = (int*)p;   p += align((size_t)(N + 1) * 4);
  int* cursor  = (int*)p;   p += align((size_t)N * 4);
  int* csr_src = (int*)p;   p += align((size_t)E * 4);
  float* bufA  = (float*)p; p += (size_t)N * 128 * 4;
  float* bufB  = (float*)p;
  // Scan scratch lives in bufA's head (dead until k_agg overwrites it).
  int* blockSums = (int*)bufA;
  int* blockOff  = blockSums + 64;

  hipMemsetAsync(cnt, 0, (size_t)N * 4, stream);

  const int nb = (N + 1023) / 1024;  // 40
  const int gemmBlocks = (N + 63) / 64;
  const int aggBlocks = (N + 3) / 4;

  // CSR build: hist -> parallel scan -> fill
  k_hist<<<(E + 255) / 256, 256, 0, stream>>>(dst, cnt, E);
  k_bsum<<<nb, 1024, 0, stream>>>(cnt, blockSums, N);
  k_bscan<<<1, 64, 0, stream>>>(blockSums, blockOff, rowptr, nb, N);
  k_escan<<<nb, 1024, 0, stream>>>(cnt, blockOff, rowptr, cursor, N);
  k_fill<<<(E + 255) / 256, 256, 0, stream>>>(src, dst, cursor, csr_src, E);

  // Layer 1
  k_agg<<<aggBlocks, 256, 0, stream>>>(x, rowptr, csr_src, bufA, N);
  k_sage_gemm<true><<<gemmBlocks, 256, 0, stream>>>(bufA, x, W1l, W1r, b1, bufB, N);

  // Layer 2
  k_agg<<<aggBlocks, 256, 0, stream>>>(bufB, rowptr, csr_src, bufA, N);
  k_sage_gemm<true><<<gemmBlocks, 256, 0, stream>>>(bufA, bufB, W2l, W2r, b2, bufB, N);

  // Output projection
  k_out_gemm<<<gemmBlocks, 256, 0, stream>>>(bufB, Wout, bout, out, N);
}